// Round 3
// baseline (847.211 us; speedup 1.0000x reference)
//
#include <hip/hip_runtime.h>
#include <math.h>

#define NIMG 8
#define NCLS 80
#define HW 40000
#define M (NCLS*HW)          // 3,200,000 per image
#define UBINS 4096           // uniform bins over s in [0,1): bin = (int)(s*4096)
#define CANDL 4096           // collect cap (fallback path)
#define SPILL_CAP 65536
#define TOPK 1000
#define OUTK 100
#define PRE_T 0.05f
#define NMS_T 0.6f
#define FLOOR_S 0.25f        // fast-path floor: verified per-call via sorted[999] >= FLOOR_BITS
#define FLOOR_BITS 0x3E800000u
#define FLOOR_SAFE 0.2494f

// device-global scratch; counters re-zeroed every call, rest guarded by counts
__device__ unsigned int       g_scnt[NIMG][32];    // padded: 128B per image
__device__ unsigned int       g_ovf[NIMG];
__device__ float              g_xthr[NIMG * HW];   // 1.25 MB, L2-resident
__device__ float              g_sct[NIMG * HW];    // exact sigmoid(centerness)
__device__ unsigned long long g_key[NIMG][SPILL_CAP];

__device__ __forceinline__ float sigmoid_exact(float x){
    return 1.0f / (1.0f + expf(-x));   // bit-matches ref (absmax 0 across sessions)
}

__device__ __forceinline__ unsigned long long shfl_xor_u64(unsigned long long v, int j){
    int lo = __shfl_xor((int)(unsigned int)(v & 0xffffffffull), j);
    int hi = __shfl_xor((int)(unsigned int)(v >> 32), j);
    return ((unsigned long long)(unsigned int)hi << 32) | (unsigned long long)(unsigned int)lo;
}

// k0: zero counters; exact sct table; xthr[hw] = logit(FLOOR_SAFE/sct), +inf if >=1.
// Spill rule x >= xthr is a strict superset of {exact score >= FLOOR_S}.
__global__ void k0_init(const float* __restrict__ cent){
    int t = blockIdx.x * blockDim.x + threadIdx.x;
    if (t < NIMG * 32) ((unsigned int*)g_scnt)[t] = 0u;
    if (t < NIMG) g_ovf[t] = 0u;
    if (t < NIMG * HW){
        float pct = sigmoid_exact(cent[t]);
        g_sct[t] = pct;
        float a = FLOOR_SAFE / pct;
        float xt;
        if (a >= 1.0f) xt = 3.0e38f;
        else {
            float am = fminf(a, 0.98f);
            xt = logf(am / (1.0f - am));
        }
        g_xthr[t] = xt;
    }
}

// k1: the ONLY full stream over cls. BARRIER-FREE this round: per-wave ballot
// compaction -> one lane-0 atomicAdd per spilling wave -> direct g_key write.
// No LDS, no __syncthreads, no per-block tail: waves retire independently.
// Key ORDER in g_key changes vs before (benign: k2 totally orders by unique key).
__global__ void __launch_bounds__(1024) k1_spill(const float* __restrict__ cls){
    const int n    = blockIdx.y;
    const int tid  = threadIdx.x;
    const int lane = tid & 63;
    const int e0   = blockIdx.x * 4096 + tid * 4;
    if (e0 >= M) return;          // whole waves only (M % 256 == 0 within block tiles)
    const int c  = e0 / HW;
    const int hw = e0 - c * HW;   // float4 never crosses a class row (HW % 4 == 0)
    float4 x  = *(const float4*)(cls + (size_t)n * M + e0);
    float4 th = *(const float4*)(g_xthr + n * HW + hw);
    #define SPILLW(J, XV, TH) { \
        bool cd2 = false; unsigned long long key_ = 0ull; \
        if (XV >= TH){ \
            float p_ = sigmoid_exact(XV); \
            if (p_ > PRE_T){ \
                float s_ = p_ * g_sct[n * HW + hw + J]; \
                key_ = ((unsigned long long)__float_as_uint(s_) << 32) \
                     | (unsigned long long)(0xFFFFFFFFu - (unsigned int)((hw + J) * NCLS + c)); \
                cd2 = true; \
            } \
        } \
        unsigned long long mk_ = __ballot(cd2); \
        if (mk_){ \
            unsigned int base_ = 0; \
            if (lane == 0) base_ = atomicAdd(&g_scnt[n][0], (unsigned int)__popcll(mk_)); \
            base_ = (unsigned int)__builtin_amdgcn_readfirstlane((int)base_); \
            if (cd2){ \
                unsigned int pos_ = base_ + (unsigned int)__popcll(mk_ & ((1ull << lane) - 1ull)); \
                if (pos_ < SPILL_CAP) g_key[n][pos_] = key_; \
                else g_ovf[n] = 1u; \
            } \
        } \
    }
    SPILLW(0, x.x, th.x)
    SPILLW(1, x.y, th.y)
    SPILLW(2, x.z, th.z)
    SPILLW(3, x.w, th.w)
    #undef SPILLW
}

struct SelPhase {
    unsigned int hist[UBINS];                 // 16 KB
    unsigned int cs[256];                     // 1 KB
    unsigned long long keysL[CANDL];          // 32 KB (fallback collect + all sort LDS steps)
};
struct NmsPhase {
    float ox1[TOPK], oy1[TOPK], ox2[TOPK], oy2[TOPK], oar[TOPK];  // offset boxes (fp32 as ref)
    float bxs[TOPK][4];
    float sc[TOPK];
    int   lab[TOPK];
    int   keeplist[OUTK];
    unsigned int  Wc[16][80];     // per-wave per-class counts -> column-exclusive prefixes
    unsigned int  ctot[80];       // class totals (input to parallel prefix)
    unsigned int  coff[81];       // class-exclusive prefix
    unsigned int  wcnt[16];       // keep-compaction wave counts -> prefix
    unsigned short ord[1024];     // class-bucketed candidate ranks (stable in rank)
    unsigned char validf[TOPK];
    unsigned char supp[TOPK];     // used by the serial-NMS fallback only
    unsigned char keepf[1024];
};
union KU { SelPhase sel; NmsPhase nms; };     // ~55 KB (phases don't overlap)

// Register/shfl bitonic step for j<=32 (partner in-wave). Element ea=tid in va,
// eb=tid+1024 in vb. Descending network: region (idx & k)==0 is descending,
// matching the LDS-step convention (up ? a<b : a>b swap) proven in Round 2.
#define REGSTEP(K_, J_) { \
    unsigned long long pa = shfl_xor_u64(va, (J_)); \
    unsigned long long pb = shfl_xor_u64(vb, (J_)); \
    bool fa = ((tid & (J_)) == 0); \
    bool da = ((tid & (K_)) == 0); \
    bool db = (((tid + 1024) & (K_)) == 0); \
    va = (fa == da) ? (va > pa ? va : pa) : (va < pa ? va : pa); \
    vb = (fa == db) ? (vb > pb ? vb : pb) : (vb < pb ? vb : pb); \
}

// k2: FAST PATH (expected always): scnt in [TOPK,2048] -> sort ALL spilled keys
// with a register/shfl bitonic (2 elems/thread; only j>=64 via LDS). Exactness
// guard: sorted elem 999 must have score >= FLOOR_S (superset property => the
// global top-1000 is entirely inside the spill set => result exact).
// On guard failure or scnt>2048: proven Round-2 machinery (hist->cut->collect->
// plain bitonic / rank; full rescan as final insurance).
__global__ void __launch_bounds__(1024) k2_select_nms(const float* __restrict__ cls,
                                                      const float* __restrict__ loc,
                                                      const float* __restrict__ reg,
                                                      const int*   __restrict__ imsz,
                                                      float* __restrict__ out){
    const int n = blockIdx.x;
    const int tid = threadIdx.x;
    const int lane = tid & 63;
    const int wv   = tid >> 6;
    __shared__ KU u;
    __shared__ unsigned long long stop[TOPK];
    __shared__ unsigned int lcnt, c025, s_cut, s_flag, s_nmsfb, s_cnt, s_aok;

    if (tid == 0){ s_nmsfb = 0u; }

    unsigned int scnt_raw = g_scnt[n][0];
    unsigned int ovf_f    = g_ovf[n];
    unsigned int S = scnt_raw < SPILL_CAP ? scnt_raw : SPILL_CAP;

    bool modeA = (!ovf_f) && (scnt_raw >= TOPK) && (scnt_raw <= 2048);
    unsigned long long kk = 0ull;
    bool needBC = true;

    if (modeA){
        // ---- direct register bitonic sort (Nsort=2048, zero-padded; 0 sorts last)
        unsigned long long va = ((unsigned int)tid < S) ? g_key[n][tid] : 0ull;
        unsigned long long vb = ((unsigned int)(tid + 1024) < S) ? g_key[n][tid + 1024] : 0ull;

        // stages k=2..64: fully in-wave (j<=32)
        REGSTEP(2,1)
        REGSTEP(4,2)  REGSTEP(4,1)
        REGSTEP(8,4)  REGSTEP(8,2)  REGSTEP(8,1)
        REGSTEP(16,8) REGSTEP(16,4) REGSTEP(16,2) REGSTEP(16,1)
        REGSTEP(32,16) REGSTEP(32,8) REGSTEP(32,4) REGSTEP(32,2) REGSTEP(32,1)
        REGSTEP(64,32) REGSTEP(64,16) REGSTEP(64,8) REGSTEP(64,4) REGSTEP(64,2) REGSTEP(64,1)

        // stages k=128..2048: j>=64 via LDS (all 1024 threads = 1024 pairs), j<=32 in-wave
        for (int k = 128; k <= 2048; k <<= 1){
            if (k == 2048){
                // j=1024: partner of elem tid is elem tid+1024 = own vb.
                // da = ((tid & 2048)==0) = true (desc) and tid is the lower index -> va=max.
                unsigned long long mx = va > vb ? va : vb;
                unsigned long long mn = va > vb ? vb : va;
                va = mx; vb = mn;
            }
            u.sel.keysL[tid] = va; u.sel.keysL[tid + 1024] = vb;
            __syncthreads();
            for (int j = (k == 2048) ? 512 : (k >> 1); j >= 64; j >>= 1){
                int i  = ((tid & ~(j - 1)) << 1) | (tid & (j - 1));
                int l  = i | j;
                unsigned long long a = u.sel.keysL[i];
                unsigned long long b = u.sel.keysL[l];
                bool up = ((i & k) == 0);
                if (up ? (a < b) : (a > b)){ u.sel.keysL[i] = b; u.sel.keysL[l] = a; }
                __syncthreads();
            }
            va = u.sel.keysL[tid]; vb = u.sel.keysL[tid + 1024];
            REGSTEP(k,32) REGSTEP(k,16) REGSTEP(k,8) REGSTEP(k,4) REGSTEP(k,2) REGSTEP(k,1)
        }
        // va = sorted element tid (descending)
        if (tid == TOPK - 1) s_aok = (((unsigned int)(va >> 32)) >= FLOOR_BITS) ? 1u : 0u;
        kk = (tid < TOPK) ? va : 0ull;
        __syncthreads();   // publishes s_aok; also fences keysL reads before NMS union writes
        needBC = (s_aok == 0u);
    }

    if (needBC){
        // ======== proven Round-2 machinery (correctness insurance) ========
        for (int i = tid; i < UBINS; i += 1024) u.sel.hist[i] = 0u;
        if (tid == 0){ lcnt = 0u; c025 = 0u; }
        if (tid < TOPK) stop[tid] = 0ull;
        __syncthreads();

        // hist pass
        for (unsigned int i = tid; i < S; i += 1024){
            unsigned long long k = g_key[n][i];
            unsigned int bits = (unsigned int)(k >> 32);
            float s = __uint_as_float(bits);
            int bin = (int)(s * 4096.0f);
            atomicAdd(&u.sel.hist[bin], 1u);
            unsigned long long mb = __ballot(bits >= FLOOR_BITS);
            if (lane == 0 && mb) atomicAdd(&c025, (unsigned int)__popcll(mb));
        }
        __syncthreads();
        if (tid < 256){
            unsigned int s = 0;
            int base = tid * 16;
            #pragma unroll
            for (int i = 0; i < 16; ++i) s += u.sel.hist[base + i];
            u.sel.cs[tid] = s;
        }
        __syncthreads();
        if (tid == 0){
            unsigned int acc = 0; int cut = 0;
            int c = 255;
            for (; c >= 0; --c){ if (acc + u.sel.cs[c] >= TOPK) break; acc += u.sel.cs[c]; }
            unsigned int Cest = 0;
            if (c >= 0){
                int b = c*16 + 15;
                for (;; --b){
                    if (acc + u.sel.hist[b] >= TOPK || b == c*16){ cut = b; break; }
                    acc += u.sel.hist[b];
                }
                Cest = acc + u.sel.hist[cut];
            }
            unsigned int fl = (scnt_raw > SPILL_CAP) || ovf_f || (c < 0) ||
                              (c025 < TOPK) || (Cest > CANDL) ? 1u : 0u;
            s_cut = (unsigned int)cut; s_flag = fl;
        }
        __syncthreads();

        if (s_flag){
            // ---- fallback: exact full rescan
            for (int i = tid; i < UBINS; i += 1024) u.sel.hist[i] = 0u;
            __syncthreads();
            const float* cls_n = cls + (size_t)n * M;
            const float* sct_n = g_sct + n * HW;
            for (int e = tid; e < M; e += 1024){
                float p = sigmoid_exact(cls_n[e]);
                if (p > PRE_T){
                    int c = e / HW; int hw = e - c * HW;
                    float s = p * sct_n[hw];
                    atomicAdd(&u.sel.hist[(int)(s * 4096.0f)], 1u);
                }
            }
            __syncthreads();
            if (tid < 256){
                unsigned int s = 0;
                int base = tid * 16;
                #pragma unroll
                for (int i = 0; i < 16; ++i) s += u.sel.hist[base + i];
                u.sel.cs[tid] = s;
            }
            __syncthreads();
            if (tid == 0){
                unsigned int acc = 0; int cut = 0; int c = 255;
                for (; c >= 0; --c){ if (acc + u.sel.cs[c] >= TOPK) break; acc += u.sel.cs[c]; }
                if (c >= 0){
                    int b = c*16 + 15;
                    for (;; --b){ acc += u.sel.hist[b]; if (acc >= TOPK || b == c*16) break; }
                    cut = b;
                }
                while (acc > CANDL && cut < UBINS){ acc -= u.sel.hist[cut]; cut++; }
                s_cut = (unsigned int)cut;
            }
            __syncthreads();
            unsigned int cutb = s_cut;
            for (int e = tid; e < M; e += 1024){
                float p = sigmoid_exact(cls_n[e]);
                if (p > PRE_T){
                    int c = e / HW; int hw = e - c * HW;
                    float s = p * sct_n[hw];
                    if ((int)(s * 4096.0f) >= (int)cutb){
                        unsigned int pos = atomicAdd(&lcnt, 1u);
                        if (pos < CANDL){
                            unsigned int idx = (unsigned int)(hw * NCLS + c);
                            u.sel.keysL[pos] = ((unsigned long long)__float_as_uint(s) << 32)
                                             | (unsigned long long)(0xFFFFFFFFu - idx);
                        }
                    }
                }
            }
        } else {
            // ---- collect keys with bin >= cut (ballot-compacted)
            unsigned int cutb = s_cut;
            for (unsigned int i = tid; i < S; i += 1024){
                unsigned long long k = g_key[n][i];
                float s = __uint_as_float((unsigned int)(k >> 32));
                bool pass = ((unsigned int)(int)(s * 4096.0f)) >= cutb;
                unsigned long long mb = __ballot(pass);
                unsigned int wcnt_ = (unsigned int)__popcll(mb);
                unsigned int base = 0;
                if (lane == 0 && wcnt_) base = atomicAdd(&lcnt, wcnt_);
                base = (unsigned int)__builtin_amdgcn_readfirstlane((int)base);
                if (pass){
                    unsigned int p = base + (unsigned int)__popcll(mb & ((1ull << lane) - 1ull));
                    if (p < CANDL) u.sel.keysL[p] = k;
                }
            }
        }
        __syncthreads();

        int C = (int)(lcnt < CANDL ? lcnt : CANDL);
        if (C <= 2048){
            int Nsort = (C <= 1024) ? 1024 : 2048;
            for (int i = C + tid; i < Nsort; i += 1024) u.sel.keysL[i] = 0ull;
            __syncthreads();
            for (int k = 2; k <= Nsort; k <<= 1){
                for (int j = k >> 1; j > 0; j >>= 1){
                    if (tid < (Nsort >> 1)){
                        int i  = ((tid & ~(j - 1)) << 1) | (tid & (j - 1));
                        int p2 = i | j;
                        unsigned long long a = u.sel.keysL[i];
                        unsigned long long b = u.sel.keysL[p2];
                        bool up = ((i & k) == 0);
                        if (up ? (a < b) : (a > b)){ u.sel.keysL[i] = b; u.sel.keysL[p2] = a; }
                    }
                    __syncthreads();
                }
            }
            if (tid < TOPK) stop[tid] = u.sel.keysL[tid];
        } else {
            for (int i = tid; i < C; i += 1024){
                unsigned long long k = u.sel.keysL[i];
                int rank = 0;
                for (int j = 0; j < C; ++j) rank += (u.sel.keysL[j] > k) ? 1 : 0;
                if (rank < TOPK) stop[rank] = k;
            }
        }
        __syncthreads();
        kk = (tid < TOPK) ? stop[tid] : 0ull;
        __syncthreads();   // ensure stop/keysL reads complete before union reuse writes
    }

    // ---- NMS phase (u.nms aliases u.sel — all sel reads are done)
    float rx1 = 0.f, ry1 = 0.f, rx2 = -1.f, ry2 = -1.f, rar = 1.f;
    float ihh = (float)imsz[2*n + 0];
    float iww = (float)imsz[2*n + 1];

    u.nms.keepf[tid] = 0;
    { unsigned int* wz = &u.nms.Wc[0][0];
      for (int i = tid; i < 16*80; i += 1024) wz[i] = 0u; }

    if (tid < TOPK){
        unsigned int bits = (unsigned int)(kk >> 32);
        float s = __uint_as_float(bits);
        u.nms.supp[tid] = 0;
        if (s > 0.0f){
            unsigned int idx = 0xFFFFFFFFu - (unsigned int)(kk & 0xFFFFFFFFull);
            int hw = (int)(idx / NCLS);
            int c  = (int)(idx % NCLS);
            int l  = c + 1;
            float x  = loc[2*hw], y = loc[2*hw + 1];
            float r0 = reg[((size_t)n*4 + 0)*HW + hw];
            float r1 = reg[((size_t)n*4 + 1)*HW + hw];
            float r2 = reg[((size_t)n*4 + 2)*HW + hw];
            float r3 = reg[((size_t)n*4 + 3)*HW + hw];
            float x1 = fminf(fmaxf(x - r0, 0.0f), iww - 1.0f);
            float y1 = fminf(fmaxf(y - r1, 0.0f), ihh - 1.0f);
            float x2 = fminf(fmaxf(x + r2, 0.0f), iww - 1.0f);
            float y2 = fminf(fmaxf(y + r3, 0.0f), ihh - 1.0f);
            u.nms.bxs[tid][0] = x1; u.nms.bxs[tid][1] = y1;
            u.nms.bxs[tid][2] = x2; u.nms.bxs[tid][3] = y2;
            float off = (float)l * 100000.0f;   // fp32, as reference (quantizes!)
            float a1 = x1 + off, b1 = y1 + off, a2 = x2 + off, b2 = y2 + off;
            float ar = (a2 - a1 + 1.0f) * (b2 - b1 + 1.0f);
            u.nms.ox1[tid] = a1; u.nms.oy1[tid] = b1;
            u.nms.ox2[tid] = a2; u.nms.oy2[tid] = b2; u.nms.oar[tid] = ar;
            rx1 = a1; ry1 = b1; rx2 = a2; ry2 = b2; rar = ar;
            u.nms.sc[tid] = s; u.nms.lab[tid] = l; u.nms.validf[tid] = 1;
        } else {
            u.nms.validf[tid] = 0; u.nms.sc[tid] = 0.0f; u.nms.lab[tid] = 0;
            u.nms.bxs[tid][0] = u.nms.bxs[tid][1] = 0.0f;
            u.nms.bxs[tid][2] = u.nms.bxs[tid][3] = 0.0f;
            u.nms.ox1[tid] = 0.f; u.nms.oy1[tid] = 0.f;
            u.nms.ox2[tid] = -1.f; u.nms.oy2[tid] = -1.f; u.nms.oar[tid] = 1.f;
        }
    }
    __syncthreads();

    // ---- class bucketing (stable in rank): counts -> column prefix -> scatter
    int mk = -1;
    if (tid < TOPK && u.nms.validf[tid]) mk = u.nms.lab[tid] - 1;
    if (mk >= 0) atomicAdd(&u.nms.Wc[wv][mk], 1u);
    __syncthreads();
    if (tid < NCLS){
        unsigned int acc = 0;
        for (int w = 0; w < 16; ++w){
            unsigned int v = u.nms.Wc[w][tid];
            u.nms.Wc[w][tid] = acc;
            acc += v;
        }
        u.nms.ctot[tid] = acc;            // class total
        if (acc > 64) atomicOr(&s_nmsfb, 1u);
    }
    __syncthreads();
    // parallel exclusive prefix over 80 class totals (each thread sums below;
    // independent LDS reads pipeline — replaces the serial tid==0 loop)
    if (tid <= NCLS){
        unsigned int acc = 0;
        for (int kq = 0; kq < tid; ++kq) acc += u.nms.ctot[kq];
        u.nms.coff[tid] = acc;
    }
    __syncthreads();

    if (!s_nmsfb){
        // stable within-wave same-class prefix via shfl (register-only)
        int below = 0;
        for (int l = 0; l < 64; ++l){
            int ok = __shfl(mk, l);
            below += (l < lane && ok == mk) ? 1 : 0;
        }
        if (mk >= 0){
            unsigned int pos = u.nms.coff[mk] + u.nms.Wc[wv][mk] + (unsigned int)below;
            u.nms.ord[pos] = (unsigned short)tid;
        }
        __syncthreads();

        // per-class greedy NMS, all in registers (wave w owns classes w, w+16, ...)
        for (int k = wv; k < NCLS; k += 16){
            int base = (int)u.nms.coff[k];
            int ck   = (int)u.nms.coff[k + 1] - base;
            if (ck <= 0) continue;
            int rr = (lane < ck) ? (int)u.nms.ord[base + lane] : -1;
            float bx1 = 0.f, by1 = 0.f, bx2 = -1.f, by2 = -1.f, bar = 1.f;
            if (rr >= 0){
                bx1 = u.nms.ox1[rr]; by1 = u.nms.oy1[rr];
                bx2 = u.nms.ox2[rr]; by2 = u.nms.oy2[rr]; bar = u.nms.oar[rr];
            }
            int sup = 0;
            for (int p = 0; p < ck; ++p){
                int keep_p = !__shfl(sup, p);          // wave-uniform
                if (keep_p){
                    float px1 = __shfl(bx1, p), py1 = __shfl(by1, p);
                    float px2 = __shfl(bx2, p), py2 = __shfl(by2, p);
                    float par = __shfl(bar, p);
                    if (lane > p && rr >= 0){
                        float ix1 = fmaxf(px1, bx1);
                        float iy1 = fmaxf(py1, by1);
                        float ix2 = fminf(px2, bx2);
                        float iy2 = fminf(py2, by2);
                        float iw_ = fmaxf(ix2 - ix1 + 1.0f, 0.0f);
                        float ih_ = fmaxf(iy2 - iy1 + 1.0f, 0.0f);
                        float inter = iw_ * ih_;
                        float iou = inter / (par + bar - inter);
                        if (iou > NMS_T) sup = 1;
                    }
                }
            }
            if (rr >= 0) u.nms.keepf[rr] = sup ? 0 : 1;
        }
        __syncthreads();

        // compact kept candidates in global rank order -> keeplist[0..cnt)
        int kf = (int)u.nms.keepf[tid];
        unsigned long long mb = __ballot(kf != 0);
        if (lane == 0) u.nms.wcnt[wv] = (unsigned int)__popcll(mb);
        __syncthreads();
        if (wv == 0){
            // wave-level shfl scan over the 16 wave counts (replaces serial tid==0)
            unsigned int v = (lane < 16) ? u.nms.wcnt[lane] : 0u;
            unsigned int orig = v;
            for (int d = 1; d < 16; d <<= 1){
                unsigned int t = __shfl_up(v, d);
                if (lane >= d) v += t;
            }
            if (lane < 16) u.nms.wcnt[lane] = v - orig;   // exclusive
            if (lane == 15) s_cnt = (v < OUTK ? v : OUTK);
        }
        __syncthreads();
        if (kf){
            unsigned int slot = u.nms.wcnt[wv] + (unsigned int)__popcll(mb & ((1ull << lane) - 1ull));
            if (slot < OUTK) u.nms.keeplist[slot] = tid;
        }
    } else {
        // ---- fallback: original serial NMS scan (c_k > 64; ~never on this data)
        int cnt = 0;
        for (int i = 0; i < TOPK; ++i){
            bool keep_i = u.nms.validf[i] && !u.nms.supp[i];
            if (keep_i){
                if (tid == 0) u.nms.keeplist[cnt] = i;
                if (tid < TOPK && tid != i){
                    float ix1 = fmaxf(u.nms.ox1[i], rx1);
                    float iy1 = fmaxf(u.nms.oy1[i], ry1);
                    float ix2 = fminf(u.nms.ox2[i], rx2);
                    float iy2 = fminf(u.nms.oy2[i], ry2);
                    float iw_ = fmaxf(ix2 - ix1 + 1.0f, 0.0f);
                    float ih_ = fmaxf(iy2 - iy1 + 1.0f, 0.0f);
                    float inter = iw_ * ih_;
                    float iou = inter / (u.nms.oar[i] + rar - inter);
                    if (iou > NMS_T) u.nms.supp[tid] = 1;
                }
                cnt++;
                __syncthreads();
                if (cnt == OUTK) break;
            }
        }
        if (tid == 0) s_cnt = (unsigned int)(cnt < OUTK ? cnt : OUTK);
    }
    __syncthreads();

    int cnt = (int)s_cnt;
    if (tid < OUTK){
        float r0=0.f,r1=0.f,r2=0.f,r3=0.f,r4=0.f,r5=0.f;
        if (tid < cnt){
            int i = u.nms.keeplist[tid];
            r0 = u.nms.bxs[i][0]; r1 = u.nms.bxs[i][1];
            r2 = u.nms.bxs[i][2]; r3 = u.nms.bxs[i][3];
            r4 = sqrtf(u.nms.sc[i]); r5 = (float)u.nms.lab[i];
        }
        float* o = out + ((size_t)n*OUTK + tid)*6;
        o[0]=r0; o[1]=r1; o[2]=r2; o[3]=r3; o[4]=r4; o[5]=r5;
    }
}

extern "C" void kernel_launch(void* const* d_in, const int* in_sizes, int n_in,
                              void* d_out, int out_size, void* d_ws, size_t ws_size,
                              hipStream_t stream){
    const float* loc  = (const float*)d_in[0];
    const float* cls  = (const float*)d_in[1];
    const float* reg  = (const float*)d_in[2];
    const float* cent = (const float*)d_in[3];
    const int*   imsz = (const int*)d_in[4];
    float* out = (float*)d_out;

    hipLaunchKernelGGL(k0_init,       dim3(625),                 dim3(512),  0, stream, cent);
    hipLaunchKernelGGL(k1_spill,      dim3((M+4095)/4096, NIMG), dim3(1024), 0, stream, cls);
    hipLaunchKernelGGL(k2_select_nms, dim3(NIMG),                dim3(1024), 0, stream,
                       cls, loc, reg, imsz, out);
}

// Round 4
// 254.613 us; speedup vs baseline: 3.3275x; 3.3275x over previous
//
#include <hip/hip_runtime.h>
#include <math.h>

#define NIMG 8
#define NCLS 80
#define HW 40000
#define M (NCLS*HW)          // 3,200,000 per image
#define UBINS 4096           // uniform bins over s in [0,1): bin = (int)(s*4096)
#define CANDL 4096           // collect cap (fallback path)
#define SPILL_CAP 65536
#define BCAP 1024
#define TOPK 1000
#define OUTK 100
#define PRE_T 0.05f
#define NMS_T 0.6f
#define FLOOR_S 0.25f        // fast-path floor: verified per-call via sorted[999] >= FLOOR_BITS
#define FLOOR_BITS 0x3E800000u
#define FLOOR_SAFE 0.2494f

// device-global scratch; counters re-zeroed every call, rest guarded by counts
__device__ unsigned int       g_scnt[NIMG][32];    // padded: 128B per image
__device__ unsigned int       g_ovf[NIMG];
__device__ float              g_xthr[NIMG * HW];   // 1.25 MB, L2-resident
__device__ float              g_sct[NIMG * HW];    // exact sigmoid(centerness)
__device__ unsigned long long g_key[NIMG][SPILL_CAP];

__device__ __forceinline__ float sigmoid_exact(float x){
    return 1.0f / (1.0f + expf(-x));   // bit-matches ref (absmax 0 across sessions)
}

__device__ __forceinline__ unsigned long long shfl_xor_u64(unsigned long long v, int j){
    int lo = __shfl_xor((int)(unsigned int)(v & 0xffffffffull), j);
    int hi = __shfl_xor((int)(unsigned int)(v >> 32), j);
    return ((unsigned long long)(unsigned int)hi << 32) | (unsigned long long)(unsigned int)lo;
}

// k0: zero counters; exact sct table; xthr[hw] = logit(FLOOR_SAFE/sct), +inf if >=1.
// Spill rule x >= xthr is a strict superset of {exact score >= FLOOR_S}.
__global__ void k0_init(const float* __restrict__ cent){
    int t = blockIdx.x * blockDim.x + threadIdx.x;
    if (t < NIMG * 32) ((unsigned int*)g_scnt)[t] = 0u;
    if (t < NIMG) g_ovf[t] = 0u;
    if (t < NIMG * HW){
        float pct = sigmoid_exact(cent[t]);
        g_sct[t] = pct;
        float a = FLOOR_SAFE / pct;
        float xt;
        if (a >= 1.0f) xt = 3.0e38f;
        else {
            float am = fminf(a, 0.98f);
            xt = logf(am / (1.0f - am));
        }
        g_xthr[t] = xt;
    }
}

// k1: REVERTED VERBATIM to the Round-2 proven form (<73 us measured).
// Round-3's "barrier-free" rewrite regressed 10x: VGPR_Count=8 + WRITE_SIZE
// 4.7MB/dispatch (~70x expected) = compiler spilled the macro-expanded
// ballot/atomic control flow to scratch; every element touch became a
// global-latency round trip (VALUBusy 1.9%). LDS staging + one block atomic
// is the proven structure — do not restructure without a measured target.
__global__ void __launch_bounds__(1024) k1_spill(const float* __restrict__ cls){
    const int n   = blockIdx.y;
    const int tid = threadIdx.x;
    const int e0  = blockIdx.x * 4096 + tid * 4;
    __shared__ unsigned long long skey[BCAP];
    __shared__ unsigned int lcnt, lbase;
    if (tid == 0) lcnt = 0u;
    __syncthreads();
    if (e0 < M){
        const int c  = e0 / HW;
        const int hw = e0 - c * HW;
        float4 x  = *(const float4*)(cls + (size_t)n * M + e0);
        float4 th = *(const float4*)(g_xthr + n * HW + hw);
        #define SPILL1(J, XV) \
        if (XV >= (J==0?th.x:J==1?th.y:J==2?th.z:th.w)){ \
            float p_ = sigmoid_exact(XV); \
            if (p_ > PRE_T){ \
                float s_ = p_ * g_sct[n * HW + hw + J]; \
                unsigned long long key_ = ((unsigned long long)__float_as_uint(s_) << 32) \
                    | (unsigned long long)(0xFFFFFFFFu - (unsigned int)((hw + J) * NCLS + c)); \
                unsigned int pp_ = atomicAdd(&lcnt, 1u); \
                if (pp_ < BCAP) skey[pp_] = key_; \
            } \
        }
        SPILL1(0, x.x)
        SPILL1(1, x.y)
        SPILL1(2, x.z)
        SPILL1(3, x.w)
        #undef SPILL1
    }
    __syncthreads();
    unsigned int raw = lcnt;
    unsigned int cnt = raw < BCAP ? raw : BCAP;
    if (tid == 0){
        lbase = cnt ? atomicAdd(&g_scnt[n][0], cnt) : 0u;
        if (raw > BCAP) g_ovf[n] = 1u;
    }
    __syncthreads();
    unsigned int base = lbase;
    for (unsigned int i = tid; i < cnt; i += 1024){
        unsigned int pos = base + i;
        if (pos < SPILL_CAP) g_key[n][pos] = skey[i];
    }
}

struct SelPhase {
    unsigned int hist[UBINS];                 // 16 KB
    unsigned int cs[256];                     // 1 KB
    unsigned long long keysL[CANDL];          // 32 KB (fallback collect + all sort LDS steps)
};
struct NmsPhase {
    float ox1[TOPK], oy1[TOPK], ox2[TOPK], oy2[TOPK], oar[TOPK];  // offset boxes (fp32 as ref)
    float bxs[TOPK][4];
    float sc[TOPK];
    int   lab[TOPK];
    int   keeplist[OUTK];
    unsigned int  Wc[16][80];     // per-wave per-class counts -> column-exclusive prefixes
    unsigned int  ctot[80];       // class totals (input to parallel prefix)
    unsigned int  coff[81];       // class-exclusive prefix
    unsigned int  wcnt[16];       // keep-compaction wave counts -> prefix
    unsigned short ord[1024];     // class-bucketed candidate ranks (stable in rank)
    unsigned char validf[TOPK];
    unsigned char supp[TOPK];     // used by the serial-NMS fallback only
    unsigned char keepf[1024];
};
union KU { SelPhase sel; NmsPhase nms; };     // ~55 KB (phases don't overlap)

// Register/shfl bitonic step for j<=32 (partner in-wave). Element ea=tid in va,
// eb=tid+1024 in vb. Descending network: region (idx & k)==0 is descending,
// matching the LDS-step convention (up ? a<b : a>b swap) proven in Round 2.
#define REGSTEP(K_, J_) { \
    unsigned long long pa = shfl_xor_u64(va, (J_)); \
    unsigned long long pb = shfl_xor_u64(vb, (J_)); \
    bool fa = ((tid & (J_)) == 0); \
    bool da = ((tid & (K_)) == 0); \
    bool db = (((tid + 1024) & (K_)) == 0); \
    va = (fa == da) ? (va > pa ? va : pa) : (va < pa ? va : pa); \
    vb = (fa == db) ? (vb > pb ? vb : pb) : (vb < pb ? vb : pb); \
}

// k2: FAST PATH (expected always): scnt in [TOPK,2048] -> sort ALL spilled keys
// with a register/shfl bitonic (2 elems/thread; only j>=64 via LDS). Exactness
// guard: sorted elem 999 must have score >= FLOOR_S (superset property => the
// global top-1000 is entirely inside the spill set => result exact).
// On guard failure or scnt>2048: proven Round-2 machinery (hist->cut->collect->
// plain bitonic / rank; full rescan as final insurance).
__global__ void __launch_bounds__(1024) k2_select_nms(const float* __restrict__ cls,
                                                      const float* __restrict__ loc,
                                                      const float* __restrict__ reg,
                                                      const int*   __restrict__ imsz,
                                                      float* __restrict__ out){
    const int n = blockIdx.x;
    const int tid = threadIdx.x;
    const int lane = tid & 63;
    const int wv   = tid >> 6;
    __shared__ KU u;
    __shared__ unsigned long long stop[TOPK];
    __shared__ unsigned int lcnt, c025, s_cut, s_flag, s_nmsfb, s_cnt, s_aok;

    if (tid == 0){ s_nmsfb = 0u; }

    unsigned int scnt_raw = g_scnt[n][0];
    unsigned int ovf_f    = g_ovf[n];
    unsigned int S = scnt_raw < SPILL_CAP ? scnt_raw : SPILL_CAP;

    bool modeA = (!ovf_f) && (scnt_raw >= TOPK) && (scnt_raw <= 2048);
    unsigned long long kk = 0ull;
    bool needBC = true;

    if (modeA){
        // ---- direct register bitonic sort (Nsort=2048, zero-padded; 0 sorts last)
        unsigned long long va = ((unsigned int)tid < S) ? g_key[n][tid] : 0ull;
        unsigned long long vb = ((unsigned int)(tid + 1024) < S) ? g_key[n][tid + 1024] : 0ull;

        // stages k=2..64: fully in-wave (j<=32)
        REGSTEP(2,1)
        REGSTEP(4,2)  REGSTEP(4,1)
        REGSTEP(8,4)  REGSTEP(8,2)  REGSTEP(8,1)
        REGSTEP(16,8) REGSTEP(16,4) REGSTEP(16,2) REGSTEP(16,1)
        REGSTEP(32,16) REGSTEP(32,8) REGSTEP(32,4) REGSTEP(32,2) REGSTEP(32,1)
        REGSTEP(64,32) REGSTEP(64,16) REGSTEP(64,8) REGSTEP(64,4) REGSTEP(64,2) REGSTEP(64,1)

        // stages k=128..2048: j>=64 via LDS (all 1024 threads = 1024 pairs), j<=32 in-wave
        for (int k = 128; k <= 2048; k <<= 1){
            if (k == 2048){
                // j=1024: partner of elem tid is elem tid+1024 = own vb.
                // da = ((tid & 2048)==0) = true (desc) and tid is the lower index -> va=max.
                unsigned long long mx = va > vb ? va : vb;
                unsigned long long mn = va > vb ? vb : va;
                va = mx; vb = mn;
            }
            u.sel.keysL[tid] = va; u.sel.keysL[tid + 1024] = vb;
            __syncthreads();
            for (int j = (k == 2048) ? 512 : (k >> 1); j >= 64; j >>= 1){
                int i  = ((tid & ~(j - 1)) << 1) | (tid & (j - 1));
                int l  = i | j;
                unsigned long long a = u.sel.keysL[i];
                unsigned long long b = u.sel.keysL[l];
                bool up = ((i & k) == 0);
                if (up ? (a < b) : (a > b)){ u.sel.keysL[i] = b; u.sel.keysL[l] = a; }
                __syncthreads();
            }
            va = u.sel.keysL[tid]; vb = u.sel.keysL[tid + 1024];
            REGSTEP(k,32) REGSTEP(k,16) REGSTEP(k,8) REGSTEP(k,4) REGSTEP(k,2) REGSTEP(k,1)
        }
        // va = sorted element tid (descending)
        if (tid == TOPK - 1) s_aok = (((unsigned int)(va >> 32)) >= FLOOR_BITS) ? 1u : 0u;
        kk = (tid < TOPK) ? va : 0ull;
        __syncthreads();   // publishes s_aok; also fences keysL reads before NMS union writes
        needBC = (s_aok == 0u);
    }

    if (needBC){
        // ======== proven Round-2 machinery (correctness insurance) ========
        for (int i = tid; i < UBINS; i += 1024) u.sel.hist[i] = 0u;
        if (tid == 0){ lcnt = 0u; c025 = 0u; }
        if (tid < TOPK) stop[tid] = 0ull;
        __syncthreads();

        // hist pass
        for (unsigned int i = tid; i < S; i += 1024){
            unsigned long long k = g_key[n][i];
            unsigned int bits = (unsigned int)(k >> 32);
            float s = __uint_as_float(bits);
            int bin = (int)(s * 4096.0f);
            atomicAdd(&u.sel.hist[bin], 1u);
            unsigned long long mb = __ballot(bits >= FLOOR_BITS);
            if (lane == 0 && mb) atomicAdd(&c025, (unsigned int)__popcll(mb));
        }
        __syncthreads();
        if (tid < 256){
            unsigned int s = 0;
            int base = tid * 16;
            #pragma unroll
            for (int i = 0; i < 16; ++i) s += u.sel.hist[base + i];
            u.sel.cs[tid] = s;
        }
        __syncthreads();
        if (tid == 0){
            unsigned int acc = 0; int cut = 0;
            int c = 255;
            for (; c >= 0; --c){ if (acc + u.sel.cs[c] >= TOPK) break; acc += u.sel.cs[c]; }
            unsigned int Cest = 0;
            if (c >= 0){
                int b = c*16 + 15;
                for (;; --b){
                    if (acc + u.sel.hist[b] >= TOPK || b == c*16){ cut = b; break; }
                    acc += u.sel.hist[b];
                }
                Cest = acc + u.sel.hist[cut];
            }
            unsigned int fl = (scnt_raw > SPILL_CAP) || ovf_f || (c < 0) ||
                              (c025 < TOPK) || (Cest > CANDL) ? 1u : 0u;
            s_cut = (unsigned int)cut; s_flag = fl;
        }
        __syncthreads();

        if (s_flag){
            // ---- fallback: exact full rescan
            for (int i = tid; i < UBINS; i += 1024) u.sel.hist[i] = 0u;
            __syncthreads();
            const float* cls_n = cls + (size_t)n * M;
            const float* sct_n = g_sct + n * HW;
            for (int e = tid; e < M; e += 1024){
                float p = sigmoid_exact(cls_n[e]);
                if (p > PRE_T){
                    int c = e / HW; int hw = e - c * HW;
                    float s = p * sct_n[hw];
                    atomicAdd(&u.sel.hist[(int)(s * 4096.0f)], 1u);
                }
            }
            __syncthreads();
            if (tid < 256){
                unsigned int s = 0;
                int base = tid * 16;
                #pragma unroll
                for (int i = 0; i < 16; ++i) s += u.sel.hist[base + i];
                u.sel.cs[tid] = s;
            }
            __syncthreads();
            if (tid == 0){
                unsigned int acc = 0; int cut = 0; int c = 255;
                for (; c >= 0; --c){ if (acc + u.sel.cs[c] >= TOPK) break; acc += u.sel.cs[c]; }
                if (c >= 0){
                    int b = c*16 + 15;
                    for (;; --b){ acc += u.sel.hist[b]; if (acc >= TOPK || b == c*16) break; }
                    cut = b;
                }
                while (acc > CANDL && cut < UBINS){ acc -= u.sel.hist[cut]; cut++; }
                s_cut = (unsigned int)cut;
            }
            __syncthreads();
            unsigned int cutb = s_cut;
            for (int e = tid; e < M; e += 1024){
                float p = sigmoid_exact(cls_n[e]);
                if (p > PRE_T){
                    int c = e / HW; int hw = e - c * HW;
                    float s = p * sct_n[hw];
                    if ((int)(s * 4096.0f) >= (int)cutb){
                        unsigned int pos = atomicAdd(&lcnt, 1u);
                        if (pos < CANDL){
                            unsigned int idx = (unsigned int)(hw * NCLS + c);
                            u.sel.keysL[pos] = ((unsigned long long)__float_as_uint(s) << 32)
                                             | (unsigned long long)(0xFFFFFFFFu - idx);
                        }
                    }
                }
            }
        } else {
            // ---- collect keys with bin >= cut (ballot-compacted)
            unsigned int cutb = s_cut;
            for (unsigned int i = tid; i < S; i += 1024){
                unsigned long long k = g_key[n][i];
                float s = __uint_as_float((unsigned int)(k >> 32));
                bool pass = ((unsigned int)(int)(s * 4096.0f)) >= cutb;
                unsigned long long mb = __ballot(pass);
                unsigned int wcnt_ = (unsigned int)__popcll(mb);
                unsigned int base = 0;
                if (lane == 0 && wcnt_) base = atomicAdd(&lcnt, wcnt_);
                base = (unsigned int)__builtin_amdgcn_readfirstlane((int)base);
                if (pass){
                    unsigned int p = base + (unsigned int)__popcll(mb & ((1ull << lane) - 1ull));
                    if (p < CANDL) u.sel.keysL[p] = k;
                }
            }
        }
        __syncthreads();

        int C = (int)(lcnt < CANDL ? lcnt : CANDL);
        if (C <= 2048){
            int Nsort = (C <= 1024) ? 1024 : 2048;
            for (int i = C + tid; i < Nsort; i += 1024) u.sel.keysL[i] = 0ull;
            __syncthreads();
            for (int k = 2; k <= Nsort; k <<= 1){
                for (int j = k >> 1; j > 0; j >>= 1){
                    if (tid < (Nsort >> 1)){
                        int i  = ((tid & ~(j - 1)) << 1) | (tid & (j - 1));
                        int p2 = i | j;
                        unsigned long long a = u.sel.keysL[i];
                        unsigned long long b = u.sel.keysL[p2];
                        bool up = ((i & k) == 0);
                        if (up ? (a < b) : (a > b)){ u.sel.keysL[i] = b; u.sel.keysL[p2] = a; }
                    }
                    __syncthreads();
                }
            }
            if (tid < TOPK) stop[tid] = u.sel.keysL[tid];
        } else {
            for (int i = tid; i < C; i += 1024){
                unsigned long long k = u.sel.keysL[i];
                int rank = 0;
                for (int j = 0; j < C; ++j) rank += (u.sel.keysL[j] > k) ? 1 : 0;
                if (rank < TOPK) stop[rank] = k;
            }
        }
        __syncthreads();
        kk = (tid < TOPK) ? stop[tid] : 0ull;
        __syncthreads();   // ensure stop/keysL reads complete before union reuse writes
    }

    // ---- NMS phase (u.nms aliases u.sel — all sel reads are done)
    float rx1 = 0.f, ry1 = 0.f, rx2 = -1.f, ry2 = -1.f, rar = 1.f;
    float ihh = (float)imsz[2*n + 0];
    float iww = (float)imsz[2*n + 1];

    u.nms.keepf[tid] = 0;
    { unsigned int* wz = &u.nms.Wc[0][0];
      for (int i = tid; i < 16*80; i += 1024) wz[i] = 0u; }

    if (tid < TOPK){
        unsigned int bits = (unsigned int)(kk >> 32);
        float s = __uint_as_float(bits);
        u.nms.supp[tid] = 0;
        if (s > 0.0f){
            unsigned int idx = 0xFFFFFFFFu - (unsigned int)(kk & 0xFFFFFFFFull);
            int hw = (int)(idx / NCLS);
            int c  = (int)(idx % NCLS);
            int l  = c + 1;
            float x  = loc[2*hw], y = loc[2*hw + 1];
            float r0 = reg[((size_t)n*4 + 0)*HW + hw];
            float r1 = reg[((size_t)n*4 + 1)*HW + hw];
            float r2 = reg[((size_t)n*4 + 2)*HW + hw];
            float r3 = reg[((size_t)n*4 + 3)*HW + hw];
            float x1 = fminf(fmaxf(x - r0, 0.0f), iww - 1.0f);
            float y1 = fminf(fmaxf(y - r1, 0.0f), ihh - 1.0f);
            float x2 = fminf(fmaxf(x + r2, 0.0f), iww - 1.0f);
            float y2 = fminf(fmaxf(y + r3, 0.0f), ihh - 1.0f);
            u.nms.bxs[tid][0] = x1; u.nms.bxs[tid][1] = y1;
            u.nms.bxs[tid][2] = x2; u.nms.bxs[tid][3] = y2;
            float off = (float)l * 100000.0f;   // fp32, as reference (quantizes!)
            float a1 = x1 + off, b1 = y1 + off, a2 = x2 + off, b2 = y2 + off;
            float ar = (a2 - a1 + 1.0f) * (b2 - b1 + 1.0f);
            u.nms.ox1[tid] = a1; u.nms.oy1[tid] = b1;
            u.nms.ox2[tid] = a2; u.nms.oy2[tid] = b2; u.nms.oar[tid] = ar;
            rx1 = a1; ry1 = b1; rx2 = a2; ry2 = b2; rar = ar;
            u.nms.sc[tid] = s; u.nms.lab[tid] = l; u.nms.validf[tid] = 1;
        } else {
            u.nms.validf[tid] = 0; u.nms.sc[tid] = 0.0f; u.nms.lab[tid] = 0;
            u.nms.bxs[tid][0] = u.nms.bxs[tid][1] = 0.0f;
            u.nms.bxs[tid][2] = u.nms.bxs[tid][3] = 0.0f;
            u.nms.ox1[tid] = 0.f; u.nms.oy1[tid] = 0.f;
            u.nms.ox2[tid] = -1.f; u.nms.oy2[tid] = -1.f; u.nms.oar[tid] = 1.f;
        }
    }
    __syncthreads();

    // ---- class bucketing (stable in rank): counts -> column prefix -> scatter
    int mk = -1;
    if (tid < TOPK && u.nms.validf[tid]) mk = u.nms.lab[tid] - 1;
    if (mk >= 0) atomicAdd(&u.nms.Wc[wv][mk], 1u);
    __syncthreads();
    if (tid < NCLS){
        unsigned int acc = 0;
        for (int w = 0; w < 16; ++w){
            unsigned int v = u.nms.Wc[w][tid];
            u.nms.Wc[w][tid] = acc;
            acc += v;
        }
        u.nms.ctot[tid] = acc;            // class total
        if (acc > 64) atomicOr(&s_nmsfb, 1u);
    }
    __syncthreads();
    // parallel exclusive prefix over 80 class totals (each thread sums below;
    // independent LDS reads pipeline — replaces the serial tid==0 loop)
    if (tid <= NCLS){
        unsigned int acc = 0;
        for (int kq = 0; kq < tid; ++kq) acc += u.nms.ctot[kq];
        u.nms.coff[tid] = acc;
    }
    __syncthreads();

    if (!s_nmsfb){
        // stable within-wave same-class prefix via shfl (register-only)
        int below = 0;
        for (int l = 0; l < 64; ++l){
            int ok = __shfl(mk, l);
            below += (l < lane && ok == mk) ? 1 : 0;
        }
        if (mk >= 0){
            unsigned int pos = u.nms.coff[mk] + u.nms.Wc[wv][mk] + (unsigned int)below;
            u.nms.ord[pos] = (unsigned short)tid;
        }
        __syncthreads();

        // per-class greedy NMS, all in registers (wave w owns classes w, w+16, ...)
        for (int k = wv; k < NCLS; k += 16){
            int base = (int)u.nms.coff[k];
            int ck   = (int)u.nms.coff[k + 1] - base;
            if (ck <= 0) continue;
            int rr = (lane < ck) ? (int)u.nms.ord[base + lane] : -1;
            float bx1 = 0.f, by1 = 0.f, bx2 = -1.f, by2 = -1.f, bar = 1.f;
            if (rr >= 0){
                bx1 = u.nms.ox1[rr]; by1 = u.nms.oy1[rr];
                bx2 = u.nms.ox2[rr]; by2 = u.nms.oy2[rr]; bar = u.nms.oar[rr];
            }
            int sup = 0;
            for (int p = 0; p < ck; ++p){
                int keep_p = !__shfl(sup, p);          // wave-uniform
                if (keep_p){
                    float px1 = __shfl(bx1, p), py1 = __shfl(by1, p);
                    float px2 = __shfl(bx2, p), py2 = __shfl(by2, p);
                    float par = __shfl(bar, p);
                    if (lane > p && rr >= 0){
                        float ix1 = fmaxf(px1, bx1);
                        float iy1 = fmaxf(py1, by1);
                        float ix2 = fminf(px2, bx2);
                        float iy2 = fminf(py2, by2);
                        float iw_ = fmaxf(ix2 - ix1 + 1.0f, 0.0f);
                        float ih_ = fmaxf(iy2 - iy1 + 1.0f, 0.0f);
                        float inter = iw_ * ih_;
                        float iou = inter / (par + bar - inter);
                        if (iou > NMS_T) sup = 1;
                    }
                }
            }
            if (rr >= 0) u.nms.keepf[rr] = sup ? 0 : 1;
        }
        __syncthreads();

        // compact kept candidates in global rank order -> keeplist[0..cnt)
        int kf = (int)u.nms.keepf[tid];
        unsigned long long mb = __ballot(kf != 0);
        if (lane == 0) u.nms.wcnt[wv] = (unsigned int)__popcll(mb);
        __syncthreads();
        if (wv == 0){
            // wave-level shfl scan over the 16 wave counts (replaces serial tid==0)
            unsigned int v = (lane < 16) ? u.nms.wcnt[lane] : 0u;
            unsigned int orig = v;
            for (int d = 1; d < 16; d <<= 1){
                unsigned int t = __shfl_up(v, d);
                if (lane >= d) v += t;
            }
            if (lane < 16) u.nms.wcnt[lane] = v - orig;   // exclusive
            if (lane == 15) s_cnt = (v < OUTK ? v : OUTK);
        }
        __syncthreads();
        if (kf){
            unsigned int slot = u.nms.wcnt[wv] + (unsigned int)__popcll(mb & ((1ull << lane) - 1ull));
            if (slot < OUTK) u.nms.keeplist[slot] = tid;
        }
    } else {
        // ---- fallback: original serial NMS scan (c_k > 64; ~never on this data)
        int cnt = 0;
        for (int i = 0; i < TOPK; ++i){
            bool keep_i = u.nms.validf[i] && !u.nms.supp[i];
            if (keep_i){
                if (tid == 0) u.nms.keeplist[cnt] = i;
                if (tid < TOPK && tid != i){
                    float ix1 = fmaxf(u.nms.ox1[i], rx1);
                    float iy1 = fmaxf(u.nms.oy1[i], ry1);
                    float ix2 = fminf(u.nms.ox2[i], rx2);
                    float iy2 = fminf(u.nms.oy2[i], ry2);
                    float iw_ = fmaxf(ix2 - ix1 + 1.0f, 0.0f);
                    float ih_ = fmaxf(iy2 - iy1 + 1.0f, 0.0f);
                    float inter = iw_ * ih_;
                    float iou = inter / (u.nms.oar[i] + rar - inter);
                    if (iou > NMS_T) u.nms.supp[tid] = 1;
                }
                cnt++;
                __syncthreads();
                if (cnt == OUTK) break;
            }
        }
        if (tid == 0) s_cnt = (unsigned int)(cnt < OUTK ? cnt : OUTK);
    }
    __syncthreads();

    int cnt = (int)s_cnt;
    if (tid < OUTK){
        float r0=0.f,r1=0.f,r2=0.f,r3=0.f,r4=0.f,r5=0.f;
        if (tid < cnt){
            int i = u.nms.keeplist[tid];
            r0 = u.nms.bxs[i][0]; r1 = u.nms.bxs[i][1];
            r2 = u.nms.bxs[i][2]; r3 = u.nms.bxs[i][3];
            r4 = sqrtf(u.nms.sc[i]); r5 = (float)u.nms.lab[i];
        }
        float* o = out + ((size_t)n*OUTK + tid)*6;
        o[0]=r0; o[1]=r1; o[2]=r2; o[3]=r3; o[4]=r4; o[5]=r5;
    }
}

extern "C" void kernel_launch(void* const* d_in, const int* in_sizes, int n_in,
                              void* d_out, int out_size, void* d_ws, size_t ws_size,
                              hipStream_t stream){
    const float* loc  = (const float*)d_in[0];
    const float* cls  = (const float*)d_in[1];
    const float* reg  = (const float*)d_in[2];
    const float* cent = (const float*)d_in[3];
    const int*   imsz = (const int*)d_in[4];
    float* out = (float*)d_out;

    hipLaunchKernelGGL(k0_init,       dim3(625),                 dim3(512),  0, stream, cent);
    hipLaunchKernelGGL(k1_spill,      dim3((M+4095)/4096, NIMG), dim3(1024), 0, stream, cls);
    hipLaunchKernelGGL(k2_select_nms, dim3(NIMG),                dim3(1024), 0, stream,
                       cls, loc, reg, imsz, out);
}